// Round 13
// baseline (122.662 us; speedup 1.0000x reference)
//
#include <hip/hip_runtime.h>
#include <hip/hip_bf16.h>

// HeadC fused: grouped 1x1-conv projections (q,k,v) + causal softmax attention.
// B=4096, T=50, N_EMBED=600, HEAD_SIZE=100, CHUNK=6. One block per batch.
// R10: NTHR 256->512 (8 waves/block), 2 blocks/CU -> 16 waves/CU (was 12).
// Tests the streaming-duty hypothesis: per-CU HBM share needs more concurrent
// load-issuing waves. Skeleton otherwise = R9: swapped-QK^T mfma(K,Q) with
// in-register softmax on waves 0-3, single post-softmax P write overlaying
// dead q rows, PV over 8 waves, 2 barriers, 39.9 KB LDS.

#define BATCH 4096
#define TT 50
#define HH 100
#define CC 600

typedef __attribute__((ext_vector_type(8))) short short8;
typedef __attribute__((ext_vector_type(4))) short short4v;
typedef __attribute__((ext_vector_type(4))) float f32x4;
typedef unsigned short ushort_t;

constexpr int NTHR = 512;
constexpr int NWAVES = 8;
constexpr float kScale = 0.04082482904638630163f;  // 600^-0.5 (folded into q)

// LDS (ushort units): 19968 us = 39936 B -> 2 blocks/CU at 512 thr (16 waves).
//   q  @ 0      [50][128] bf16, granule XOR swizzle (row&7). Row t's cols 0..63
//               overlaid by P[t][s] post-softmax (per-lane, race-free).
//   k  @ 6400   [50][128]  (A-frag rows 50..63 spill into vT: junk, masked)
//   vT @ 12800  [100][64]  (vT[h][t]; cols 52..63 zeroed; rows 100..111 spill
//               into pad -> junk only in discarded h>=100 D-cols)
//   pad@ 19200  768 us (junk OK)
constexpr int RQ = 0, RK = 6400, RV = 12800, LDS_US = 19968;

__device__ __forceinline__ ushort_t f2bf(float f) {
    return __builtin_bit_cast(ushort_t, __float2bfloat16(f));
}
// barrier without vmcnt drain (LDS ordering only)
__device__ __forceinline__ void bar_lds() {
    asm volatile("s_waitcnt lgkmcnt(0)" ::: "memory");
    __builtin_amdgcn_s_barrier();
    asm volatile("" ::: "memory");
}

__global__ __launch_bounds__(NTHR, 4) void headc_fused(
    const float* __restrict__ x,
    const float* __restrict__ wq,
    const float* __restrict__ wk,
    const float* __restrict__ wv,
    float* __restrict__ out)
{
    __shared__ __align__(16) ushort_t lds[LDS_US];

    const int tid = threadIdx.x;
    const int b = blockIdx.x;
    const float* xb = x + (size_t)b * (TT * CC);

    // ---- pad zeroing (concurrent with phase 1; granules disjoint from proj writes) ----
    {
        const short8 z8 = {0, 0, 0, 0, 0, 0, 0, 0};
        const short4v z4 = {0, 0, 0, 0};
        if (tid >= 256 && tid < 456) {
            const int j = tid - 256;
            if (j < 100) {  // q/k K-pad cols 100..127 (logical granule 12-hi, 13..15)
                const int arr = j / 50;
                const int r = j % 50;
                const int base = (arr ? RK : RQ) + r * 128;
                *reinterpret_cast<short4v*>(lds + base + ((12 ^ (r & 7)) << 3) + 4) = z4;
                *reinterpret_cast<short8*>(lds + base + ((13 ^ (r & 7)) << 3)) = z8;
                *reinterpret_cast<short8*>(lds + base + ((14 ^ (r & 7)) << 3)) = z8;
                *reinterpret_cast<short8*>(lds + base + ((15 ^ (r & 7)) << 3)) = z8;
            } else {          // vT K-pad cols t=52..63 (granule 6-hi, 7)
                const int h = j - 100;
                const int base = RV + h * 64;
                *reinterpret_cast<short4v*>(lds + base + ((6 ^ (h & 7)) << 3) + 4) = z4;
                *reinterpret_cast<short8*>(lds + base + ((7 ^ (h & 7)) << 3)) = z8;
            }
        }
    }

    // ---- phase 1: projections. hp pinned; c = tid/50 in 0..9; qd set:
    // {c} plus {c+10} for c<3 (13 qd groups over 500 threads). ----
    const int hp = tid % 50;
    const int c = tid / 50;            // 0..10 (c==10 -> inactive)
    const int h0 = hp * 2;
    const bool pactive = (tid < 500);

    if (pactive) {
        const float4 w0 = *(const float4*)(wq + h0 * 6);
        const float4 w1 = *(const float4*)(wq + h0 * 6 + 4);
        const float4 w2 = *(const float4*)(wq + h0 * 6 + 8);
        const float4 w3 = *(const float4*)(wk + h0 * 6);
        const float4 w4 = *(const float4*)(wk + h0 * 6 + 4);
        const float4 w5 = *(const float4*)(wk + h0 * 6 + 8);
        const float4 w6 = *(const float4*)(wv + h0 * 6);
        const float4 w7 = *(const float4*)(wv + h0 * 6 + 4);
        const float4 w8 = *(const float4*)(wv + h0 * 6 + 8);

        float4 xr[4][3];

        auto issue = [&](int qd) {
            const int tb = qd * 4;
            #pragma unroll
            for (int r = 0; r < 4; ++r) {
                const int tc = (tb + r < TT) ? (tb + r) : (TT - 1);
                const float* xp = xb + tc * CC + h0 * 6;   // 48B/lane, coalesced
                xr[r][0] = *(const float4*)xp;
                xr[r][1] = *(const float4*)(xp + 4);
                xr[r][2] = *(const float4*)(xp + 8);
            }
        };
        auto proj = [&](int qd) {
            const int tb = qd * 4;
            short4v vp0 = {0, 0, 0, 0}, vp1 = {0, 0, 0, 0};
            #pragma unroll
            for (int r = 0; r < 4; ++r) {
                const int t = tb + r;
                const float4 xa = xr[r][0], xm = xr[r][1], xc = xr[r][2];
                float q0 = xa.x*w0.x + xa.y*w0.y + xa.z*w0.z + xa.w*w0.w + xm.x*w1.x + xm.y*w1.y;
                float q1 = xm.z*w1.z + xm.w*w1.w + xc.x*w2.x + xc.y*w2.y + xc.z*w2.z + xc.w*w2.w;
                float k0 = xa.x*w3.x + xa.y*w3.y + xa.z*w3.z + xa.w*w3.w + xm.x*w4.x + xm.y*w4.y;
                float k1 = xm.z*w4.z + xm.w*w4.w + xc.x*w5.x + xc.y*w5.y + xc.z*w5.z + xc.w*w5.w;
                float v0 = xa.x*w6.x + xa.y*w6.y + xa.z*w6.z + xa.w*w6.w + xm.x*w7.x + xm.y*w7.y;
                float v1 = xm.z*w7.z + xm.w*w7.w + xc.x*w8.x + xc.y*w8.y + xc.z*w8.z + xc.w*w8.w;
                q0 *= kScale; q1 *= kScale;
                if (t < TT) {
                    const int qg = (((h0 >> 3) ^ (t & 7)) << 3) + (h0 & 7);
                    *reinterpret_cast<unsigned*>(lds + RQ + t * 128 + qg) =
                        (unsigned)f2bf(q0) | ((unsigned)f2bf(q1) << 16);
                    *reinterpret_cast<unsigned*>(lds + RK + t * 128 + qg) =
                        (unsigned)f2bf(k0) | ((unsigned)f2bf(k1) << 16);
                    vp0[r] = (short)f2bf(v0);
                    vp1[r] = (short)f2bf(v1);
                }
            }
            const int g = qd >> 1, half = (qd & 1) * 4;
            *reinterpret_cast<short4v*>(lds + RV + h0 * 64 + ((g ^ (h0 & 7)) << 3) + half) = vp0;
            *reinterpret_cast<short4v*>(lds + RV + (h0 + 1) * 64 + ((g ^ ((h0 + 1) & 7)) << 3) + half) = vp1;
        };

        issue(c);
        proj(c);
        if (c < 3) {
            issue(c + 10);
            proj(c + 10);
        }
    }
    bar_lds();   // barrier 1: q,k,vT ready

    const int w = tid >> 6;
    const int lane = tid & 63;
    const int l15 = lane & 15, l4 = lane >> 4;

    // ---- phase 2 (waves 0-3): S^T = K*Q^T, in-reg softmax, P overlay write ----
    if (w < 4) {
        const int t = w * 16 + l15;        // this lane's output row

        short8 qf[4];
        #pragma unroll
        for (int kk = 0; kk < 4; ++kk)
            qf[kk] = *reinterpret_cast<const short8*>(lds + RQ + t * 128 + (((kk * 4 + l4) ^ (t & 7)) << 3));

        f32x4 sacc[4];
        #pragma unroll
        for (int sm = 0; sm < 4; ++sm) {
            f32x4 a = {0.f, 0.f, 0.f, 0.f};
            if (sm <= w) {
                const int ar = sm * 16 + l15;   // k row (s); rows>=50 junk -> masked
                #pragma unroll
                for (int kk = 0; kk < 4; ++kk) {
                    const short8 kf = *reinterpret_cast<const short8*>(lds + RK + ar * 128 + (((kk * 4 + l4) ^ (ar & 7)) << 3));
                    a = __builtin_amdgcn_mfma_f32_16x16x32_bf16(kf, qf[kk], a, 0, 0, 0);
                }
            }
            sacc[sm] = a;   // sacc[sm][r] = S[t][sm*16 + l4*4 + r]
        }

        float mx = -3.4e38f;
        #pragma unroll
        for (int sm = 0; sm < 4; ++sm) {
            #pragma unroll
            for (int r = 0; r < 4; ++r) {
                const int s = sm * 16 + l4 * 4 + r;
                if (sm <= w && s <= t) mx = fmaxf(mx, sacc[sm][r]);
            }
        }
        mx = fmaxf(mx, __shfl_xor(mx, 16));
        mx = fmaxf(mx, __shfl_xor(mx, 32));
        float sum = 0.f;
        #pragma unroll
        for (int sm = 0; sm < 4; ++sm) {
            #pragma unroll
            for (int r = 0; r < 4; ++r) {
                const int s = sm * 16 + l4 * 4 + r;
                const float e = (sm <= w && s <= t) ? __expf(sacc[sm][r] - mx) : 0.f;
                sacc[sm][r] = e;
                sum += e;
            }
        }
        sum += __shfl_xor(sum, 16);
        sum += __shfl_xor(sum, 32);
        const float inv = 1.f / sum;

        if (t < TT) {   // t>=50 must not write (would corrupt k rows 0..13)
            #pragma unroll
            for (int sm = 0; sm < 4; ++sm) {
                #pragma unroll
                for (int rp = 0; rp < 2; ++rp) {
                    const int s0 = sm * 16 + l4 * 4 + 2 * rp;
                    const unsigned pk = (unsigned)f2bf(sacc[sm][2 * rp] * inv)
                                      | ((unsigned)f2bf(sacc[sm][2 * rp + 1] * inv) << 16);
                    *reinterpret_cast<unsigned*>(lds + RQ + t * 128 + (((s0 >> 3) ^ (t & 7)) << 3) + (s0 & 7)) = pk;
                }
            }
        }
    }
    bar_lds();   // barrier 2: P ready (q region rows t<50, cols 0..63)

    // ---- phase 3: O = P*V via MFMA, 4x7 tiles over 8 waves, K=64 ----
    float* ob = out + (size_t)b * (TT * HH);
    for (int p = w; p < 28; p += NWAVES) {
        const int tm = p / 7, hn = p - tm * 7;
        f32x4 acc = {0.f, 0.f, 0.f, 0.f};
        const int ar = tm * 16 + l15;   // P row (rows>=50 junk -> discarded)
        const int br = hn * 16 + l15;   // vT row (h; rows>=100 junk -> discarded cols)
        #pragma unroll
        for (int kk = 0; kk < 2; ++kk) {
            const int g = kk * 4 + l4;
            const short8 a  = *reinterpret_cast<const short8*>(lds + RQ + ar * 128 + ((g ^ (ar & 7)) << 3));
            const short8 bb = *reinterpret_cast<const short8*>(lds + RV + br * 64 + ((g ^ (br & 7)) << 3));
            acc = __builtin_amdgcn_mfma_f32_16x16x32_bf16(a, bb, acc, 0, 0, 0);
        }
        const int h = hn * 16 + l15;
        const int t0 = tm * 16 + l4 * 4;
        if (h < HH) {
            #pragma unroll
            for (int r = 0; r < 4; ++r) {
                const int tt = t0 + r;
                if (tt < TT) ob[tt * HH + h] = acc[r];
            }
        }
    }
}

extern "C" void kernel_launch(void* const* d_in, const int* in_sizes, int n_in,
                              void* d_out, int out_size, void* d_ws, size_t ws_size,
                              hipStream_t stream) {
    const float* x  = (const float*)d_in[0];
    const float* wq = (const float*)d_in[1];
    const float* wk = (const float*)d_in[2];
    const float* wv = (const float*)d_in[3];
    float* out = (float*)d_out;
    headc_fused<<<dim3(BATCH), dim3(NTHR), 0, stream>>>(x, wq, wk, wv, out);
}

// Round 14
// 122.631 us; speedup vs baseline: 1.0003x; 1.0003x over previous
//
#include <hip/hip_runtime.h>
#include <hip/hip_bf16.h>

// HeadC fused: grouped 1x1-conv projections (q,k,v) + causal softmax attention.
// B=4096, T=50, N_EMBED=600, HEAD_SIZE=100, CHUNK=6. One block per batch.
// R11: single-barrier skeleton. Swapped-QK^T (mfma(K,Q)) with in-register
// softmax; P overlaid on dead q rows. PV restricted to the wave's OWN t-block
// (tm = wave id) so all P reads are same-wave writes -> barrier 2 replaced by
// s_waitcnt lgkmcnt(0). Waves fully decouple after barrier 1.

#define BATCH 4096
#define TT 50
#define HH 100
#define CC 600

typedef __attribute__((ext_vector_type(8))) short short8;
typedef __attribute__((ext_vector_type(4))) short short4v;
typedef __attribute__((ext_vector_type(4))) float f32x4;
typedef unsigned short ushort_t;

constexpr int NTHR = 256;
constexpr float kScale = 0.04082482904638630163f;  // 600^-0.5 (folded into q)

// LDS (ushort units): 19968 us = 39936 B -> 3 blocks/CU at 256 thr.
//   q  @ 0      [50][128] bf16, granule XOR swizzle (row&7). Row t's cols 0..63
//               overlaid by P[t][s] post-softmax (same-lane/same-wave, race-free).
//   k  @ 6400   [50][128]  (A-frag rows 50..63 spill into vT: junk, masked)
//   vT @ 12800  [100][64]  (vT[h][t]; cols 52..63 zeroed; rows 100..111 spill
//               into pad -> junk only in discarded h>=100 D-cols)
//   pad@ 19200  768 us (junk OK)
constexpr int RQ = 0, RK = 6400, RV = 12800, LDS_US = 19968;

__device__ __forceinline__ ushort_t f2bf(float f) {
    return __builtin_bit_cast(ushort_t, __float2bfloat16(f));
}
// barrier without vmcnt drain (LDS ordering only)
__device__ __forceinline__ void bar_lds() {
    asm volatile("s_waitcnt lgkmcnt(0)" ::: "memory");
    __builtin_amdgcn_s_barrier();
    asm volatile("" ::: "memory");
}

__global__ __launch_bounds__(NTHR, 3) void headc_fused(
    const float* __restrict__ x,
    const float* __restrict__ wq,
    const float* __restrict__ wk,
    const float* __restrict__ wv,
    float* __restrict__ out)
{
    __shared__ __align__(16) ushort_t lds[LDS_US];

    const int tid = threadIdx.x;
    const int b = blockIdx.x;
    const float* xb = x + (size_t)b * (TT * CC);

    // ---- pad zeroing (concurrent with phase 1; granules disjoint from proj writes) ----
    {
        const short8 z8 = {0, 0, 0, 0, 0, 0, 0, 0};
        const short4v z4 = {0, 0, 0, 0};
        if (tid < 200) {
            if (tid < 100) {  // q/k K-pad cols 100..127 (logical granule 12-hi, 13..15)
                const int arr = tid / 50;
                const int r = tid % 50;
                const int base = (arr ? RK : RQ) + r * 128;
                *reinterpret_cast<short4v*>(lds + base + ((12 ^ (r & 7)) << 3) + 4) = z4;
                *reinterpret_cast<short8*>(lds + base + ((13 ^ (r & 7)) << 3)) = z8;
                *reinterpret_cast<short8*>(lds + base + ((14 ^ (r & 7)) << 3)) = z8;
                *reinterpret_cast<short8*>(lds + base + ((15 ^ (r & 7)) << 3)) = z8;
            } else {          // vT K-pad cols t=52..63 (granule 6-hi, 7)
                const int h = tid - 100;
                const int base = RV + h * 64;
                *reinterpret_cast<short4v*>(lds + base + ((6 ^ (h & 7)) << 3) + 4) = z4;
                *reinterpret_cast<short8*>(lds + base + ((7 ^ (h & 7)) << 3)) = z8;
            }
        }
    }

    // ---- phase 1: projections, hp pinned, 2-deep load pipeline over qd ----
    const int hp = tid % 50;
    const int c = tid / 50;            // 0..5 (c==5 inactive)
    const int h0 = hp * 2;
    const bool pactive = (tid < 250);
    const bool has3 = (c < 3);         // qd set {c, c+5} (+ {c+10} if c<3)

    if (pactive) {
        const float4 w0 = *(const float4*)(wq + h0 * 6);
        const float4 w1 = *(const float4*)(wq + h0 * 6 + 4);
        const float4 w2 = *(const float4*)(wq + h0 * 6 + 8);
        const float4 w3 = *(const float4*)(wk + h0 * 6);
        const float4 w4 = *(const float4*)(wk + h0 * 6 + 4);
        const float4 w5 = *(const float4*)(wk + h0 * 6 + 8);
        const float4 w6 = *(const float4*)(wv + h0 * 6);
        const float4 w7 = *(const float4*)(wv + h0 * 6 + 4);
        const float4 w8 = *(const float4*)(wv + h0 * 6 + 8);

        float4 xA[4][3], xB[4][3];

        auto issue = [&](float4 (&xr)[4][3], int qd) {
            const int tb = qd * 4;
            #pragma unroll
            for (int r = 0; r < 4; ++r) {
                const int tc = (tb + r < TT) ? (tb + r) : (TT - 1);
                const float* xp = xb + tc * CC + h0 * 6;   // 48B/lane, coalesced
                xr[r][0] = *(const float4*)xp;
                xr[r][1] = *(const float4*)(xp + 4);
                xr[r][2] = *(const float4*)(xp + 8);
            }
        };
        auto proj = [&](const float4 (&xr)[4][3], int qd) {
            const int tb = qd * 4;
            short4v vp0 = {0, 0, 0, 0}, vp1 = {0, 0, 0, 0};
            #pragma unroll
            for (int r = 0; r < 4; ++r) {
                const int t = tb + r;
                const float4 xa = xr[r][0], xm = xr[r][1], xc = xr[r][2];
                float q0 = xa.x*w0.x + xa.y*w0.y + xa.z*w0.z + xa.w*w0.w + xm.x*w1.x + xm.y*w1.y;
                float q1 = xm.z*w1.z + xm.w*w1.w + xc.x*w2.x + xc.y*w2.y + xc.z*w2.z + xc.w*w2.w;
                float k0 = xa.x*w3.x + xa.y*w3.y + xa.z*w3.z + xa.w*w3.w + xm.x*w4.x + xm.y*w4.y;
                float k1 = xm.z*w4.z + xm.w*w4.w + xc.x*w5.x + xc.y*w5.y + xc.z*w5.z + xc.w*w5.w;
                float v0 = xa.x*w6.x + xa.y*w6.y + xa.z*w6.z + xa.w*w6.w + xm.x*w7.x + xm.y*w7.y;
                float v1 = xm.z*w7.z + xm.w*w7.w + xc.x*w8.x + xc.y*w8.y + xc.z*w8.z + xc.w*w8.w;
                q0 *= kScale; q1 *= kScale;
                if (t < TT) {
                    const int qg = (((h0 >> 3) ^ (t & 7)) << 3) + (h0 & 7);
                    *reinterpret_cast<unsigned*>(lds + RQ + t * 128 + qg) =
                        (unsigned)f2bf(q0) | ((unsigned)f2bf(q1) << 16);
                    *reinterpret_cast<unsigned*>(lds + RK + t * 128 + qg) =
                        (unsigned)f2bf(k0) | ((unsigned)f2bf(k1) << 16);
                    vp0[r] = (short)f2bf(v0);
                    vp1[r] = (short)f2bf(v1);
                }
            }
            const int g = qd >> 1, half = (qd & 1) * 4;
            *reinterpret_cast<short4v*>(lds + RV + h0 * 64 + ((g ^ (h0 & 7)) << 3) + half) = vp0;
            *reinterpret_cast<short4v*>(lds + RV + (h0 + 1) * 64 + ((g ^ ((h0 + 1) & 7)) << 3) + half) = vp1;
        };

        issue(xA, c);
        issue(xB, c + 5);
        proj(xA, c);
        if (has3) issue(xA, c + 10);
        proj(xB, c + 5);
        if (has3) proj(xA, c + 10);
    }
    bar_lds();   // barrier 1 (the only barrier): q,k,vT ready

    const int w = tid >> 6;
    const int lane = tid & 63;
    const int l15 = lane & 15, l4 = lane >> 4;
    const int t = w * 16 + l15;        // this lane's output row

    // ---- phase 2: S^T = K*Q^T (wave w owns t-block w), in-reg softmax,
    //      P write overlaying dead q rows (same-wave data only) ----
    {
        short8 qf[4];
        #pragma unroll
        for (int kk = 0; kk < 4; ++kk)
            qf[kk] = *reinterpret_cast<const short8*>(lds + RQ + t * 128 + (((kk * 4 + l4) ^ (t & 7)) << 3));

        f32x4 sacc[4];
        #pragma unroll
        for (int sm = 0; sm < 4; ++sm) {
            f32x4 a = {0.f, 0.f, 0.f, 0.f};
            if (sm <= w) {
                const int ar = sm * 16 + l15;   // k row (s); rows>=50 junk -> masked
                #pragma unroll
                for (int kk = 0; kk < 4; ++kk) {
                    const short8 kf = *reinterpret_cast<const short8*>(lds + RK + ar * 128 + (((kk * 4 + l4) ^ (ar & 7)) << 3));
                    a = __builtin_amdgcn_mfma_f32_16x16x32_bf16(kf, qf[kk], a, 0, 0, 0);
                }
            }
            sacc[sm] = a;   // sacc[sm][r] = S[t][sm*16 + l4*4 + r]
        }

        float mx = -3.4e38f;
        #pragma unroll
        for (int sm = 0; sm < 4; ++sm) {
            #pragma unroll
            for (int r = 0; r < 4; ++r) {
                const int s = sm * 16 + l4 * 4 + r;
                if (sm <= w && s <= t) mx = fmaxf(mx, sacc[sm][r]);
            }
        }
        mx = fmaxf(mx, __shfl_xor(mx, 16));
        mx = fmaxf(mx, __shfl_xor(mx, 32));
        float sum = 0.f;
        #pragma unroll
        for (int sm = 0; sm < 4; ++sm) {
            #pragma unroll
            for (int r = 0; r < 4; ++r) {
                const int s = sm * 16 + l4 * 4 + r;
                const float e = (sm <= w && s <= t) ? __expf(sacc[sm][r] - mx) : 0.f;
                sacc[sm][r] = e;
                sum += e;
            }
        }
        sum += __shfl_xor(sum, 16);
        sum += __shfl_xor(sum, 32);
        const float inv = 1.f / sum;

        if (t < TT) {   // t>=50 must not write (would corrupt k rows 0..13)
            #pragma unroll
            for (int sm = 0; sm < 4; ++sm) {
                #pragma unroll
                for (int rp = 0; rp < 2; ++rp) {
                    const int s0 = sm * 16 + l4 * 4 + 2 * rp;
                    const unsigned pk = (unsigned)f2bf(sacc[sm][2 * rp] * inv)
                                      | ((unsigned)f2bf(sacc[sm][2 * rp + 1] * inv) << 16);
                    *reinterpret_cast<unsigned*>(lds + RQ + t * 128 + (((s0 >> 3) ^ (t & 7)) << 3) + (s0 & 7)) = pk;
                }
            }
        }
    }

    // Same-wave LDS ordering: P writes (above) -> P reads (below). No barrier.
    asm volatile("s_waitcnt lgkmcnt(0)" ::: "memory");
    __builtin_amdgcn_sched_barrier(0);

    // ---- phase 3: O = P*V for the wave's OWN t-block (tm = w), 7 hn tiles ----
    float* ob = out + (size_t)b * (TT * HH);
    {
        const int ar = w * 16 + l15;       // P row (rows>=50 stale-q junk -> discarded)
        const int t0 = w * 16 + l4 * 4;
        #pragma unroll
        for (int hn = 0; hn < 7; ++hn) {
            f32x4 acc = {0.f, 0.f, 0.f, 0.f};
            const int br = hn * 16 + l15;  // vT row (h; rows>=100 junk -> discarded cols)
            #pragma unroll
            for (int kk = 0; kk < 2; ++kk) {
                const int g = kk * 4 + l4;
                const short8 a  = *reinterpret_cast<const short8*>(lds + RQ + ar * 128 + ((g ^ (ar & 7)) << 3));
                const short8 bb = *reinterpret_cast<const short8*>(lds + RV + br * 64 + ((g ^ (br & 7)) << 3));
                acc = __builtin_amdgcn_mfma_f32_16x16x32_bf16(a, bb, acc, 0, 0, 0);
            }
            const int h = hn * 16 + l15;
            if (h < HH) {
                #pragma unroll
                for (int r = 0; r < 4; ++r) {
                    const int tt = t0 + r;
                    if (tt < TT) ob[tt * HH + h] = acc[r];
                }
            }
        }
    }
}

extern "C" void kernel_launch(void* const* d_in, const int* in_sizes, int n_in,
                              void* d_out, int out_size, void* d_ws, size_t ws_size,
                              hipStream_t stream) {
    const float* x  = (const float*)d_in[0];
    const float* wq = (const float*)d_in[1];
    const float* wk = (const float*)d_in[2];
    const float* wv = (const float*)d_in[3];
    float* out = (float*)d_out;
    headc_fused<<<dim3(BATCH), dim3(NTHR), 0, stream>>>(x, wq, wk, wv, out);
}